// Round 1
// 436.238 us; speedup vs baseline: 1.0342x; 1.0342x over previous
//
#include <hip/hip_runtime.h>
#include <stdint.h>

// Problem constants (match reference)
#define NE   64      // experts
#define HD   2048    // hidden dim
#define ND   512     // difficulty head inner dim
#define NTOK 16384   // B*S = 4*4096

typedef __attribute__((ext_vector_type(4))) float   fv4;
typedef __attribute__((ext_vector_type(8))) short   bf16x8;
typedef __attribute__((ext_vector_type(4))) float   f32x4;

// LDS 16B-unit index: row*4 + (q ^ ((row>>2)&3)).
__device__ inline int swz(int row, int q) {
  return row * 4 + (q ^ ((row >> 2) & 3));
}

// ---------- helpers ----------
__device__ inline unsigned short bf_rne(float x) {
  unsigned int u = __float_as_uint(x);
  return (unsigned short)((u + 0x7FFFu + ((u >> 16) & 1u)) >> 16);
}
__device__ inline float bf_to_f(unsigned short h) {
  return __uint_as_float((unsigned int)h << 16);
}
// exact 3-way truncation split: x == h + m + l (8+8+8 mantissa bits)
__device__ inline void split3(float x, unsigned short& h, unsigned short& m,
                              unsigned short& l) {
  unsigned int u = __float_as_uint(x);
  h = (unsigned short)(u >> 16);
  float r1 = x - __uint_as_float(u & 0xFFFF0000u);
  unsigned int um = __float_as_uint(r1);
  m = (unsigned short)(um >> 16);
  float r2 = r1 - __uint_as_float(um & 0xFFFF0000u);
  l = bf_rne(r2);
}

// async global->LDS 16B copy. Dest must be wave-uniform base + lane*16,
// which both B-staging loops satisfy (unit index = wave*64 + lane [+ j*256]).
// Source address is per-lane (swizzle folded into the global address).
__device__ inline void gload16(const void* g, void* l) {
  __builtin_amdgcn_global_load_lds(
      (__attribute__((address_space(1))) void*)g,
      (__attribute__((address_space(3))) void*)l, 16, 0, 0);
}

// ---------- K0: fused zero + w1 split + gw split3 (independent writes) ----
__global__ __launch_bounds__(256)
void k_pre(uint4* __restrict__ z16, const float* __restrict__ w1,
           unsigned short* __restrict__ w1h, unsigned short* __restrict__ w1l,
           const float* __restrict__ gw, unsigned short* __restrict__ gh,
           unsigned short* __restrict__ gm, unsigned short* __restrict__ gl) {
  const int b = blockIdx.x, t = threadIdx.x;
  if (b < 1040) {
    // zero lg + x2/tpe/ks_es: 4,260,368 B = 266,273 uint4
    uint4 zz = {0u, 0u, 0u, 0u};
    for (int i = b * 256 + t; i < 266273; i += 1040 * 256) z16[i] = zz;
  } else if (b < 1552) {
    // w1 fp32 -> bf16 hi/lo planes (rne)
    int i = ((b - 1040) * 256 + t) * 8;
    fv4 v0 = *(const fv4*)(w1 + i);
    fv4 v1 = *(const fv4*)(w1 + i + 4);
    union { unsigned short s[8]; uint4 v; } ph, pl;
#pragma unroll
    for (int j = 0; j < 8; ++j) {
      float x = (j < 4) ? v0[j] : v1[j - 4];
      unsigned short h = bf_rne(x);
      ph.s[j] = h;
      pl.s[j] = bf_rne(x - bf_to_f(h));
    }
    *(uint4*)(w1h + i) = ph.v;
    *(uint4*)(w1l + i) = pl.v;
  } else {
    // gw fp32 -> 3 exact bf16 planes (h/m/l truncation split)
    int i = ((b - 1552) * 256 + t) * 8;
    fv4 v0 = *(const fv4*)(gw + i);
    fv4 v1 = *(const fv4*)(gw + i + 4);
    union { unsigned short s[8]; uint4 v; } xh, xm, xl;
#pragma unroll
    for (int j = 0; j < 8; ++j) {
      float x = (j < 4) ? v0[j] : v1[j - 4];
      split3(x, xh.s[j], xm.s[j], xl.s[j]);
    }
    *(uint4*)(gh + i) = xh.v;
    *(uint4*)(gm + i) = xm.v;
    *(uint4*)(gl + i) = xl.v;
  }
}

// ---------- K1: fused gate + difficulty GEMMs ----------
// blockIdx.z == 0 -> gate body (bit-identical to prior k_gate)
// blockIdx.z == 1 -> diff body (bit-identical to prior k_diff)
// grid (2, 256, 2) = 1024 blocks -> 4 blocks/CU (4 x 40KB LDS = 160KB exact),
// doubling occupancy vs the two grid-capped 512-block kernels, and mixing
// VALU-heavy gate waves with MFMA-heavy diff waves on each SIMD.
// B-plane staging in both bodies is pure 16B copies -> global_load_lds.
__global__ __launch_bounds__(256)
void k_main(const float* __restrict__ hs, const unsigned short* __restrict__ gh,
            const unsigned short* __restrict__ gm,
            const unsigned short* __restrict__ gl, float* __restrict__ lg,
            const unsigned short* __restrict__ w1h,
            const unsigned short* __restrict__ w1l, const float* __restrict__ b1,
            const float* __restrict__ w2, float* __restrict__ x2) {
  __shared__ __align__(16) unsigned short smem[20480];  // 40 KB union

  const int t = threadIdx.x;
  const int w = t >> 6, l = t & 63, l15 = l & 15, q = l >> 4;
  const int srow = t >> 2, sq = (t & 3) ^ ((t >> 4) & 3);
  const int tokBase = blockIdx.y * 64;

  if (blockIdx.z == 0) {
    // ================= gate body =================
    unsigned short* sAh = smem;          // 256 units x 8 shorts
    unsigned short* sAm = smem + 2048;
    unsigned short* sAl = smem + 4096;
    unsigned short* sBh = smem + 6144;
    unsigned short* sBm = smem + 8192;
    unsigned short* sBl = smem + 10240;

    const int k0base = blockIdx.x * (HD / 2);
    const int waveM = w & 1, waveN = w >> 1;

    f32x4 acc[2][2] = {};

    for (int kb = 0; kb < 32; ++kb) {
      const int k0 = k0base + kb * 32;
      // A: fp32 load (issued first), split3 inline, ds_write
      const float* ga = hs + (size_t)(tokBase + srow) * HD + k0 + sq * 8;
      fv4 a0 = *(const fv4*)ga, a1 = *(const fv4*)(ga + 4);
      // B: 3 pre-split planes, async 16B DMA into linear LDS
      {
        const size_t gb = (size_t)srow * HD + k0 + sq * 8;
        gload16(gh + gb, &sBh[t * 8]);
        gload16(gm + gb, &sBm[t * 8]);
        gload16(gl + gb, &sBl[t * 8]);
      }
      {
        union { unsigned short s[8]; uint4 v; } xh, xm, xl;
#pragma unroll
        for (int j = 0; j < 8; ++j) {
          float x = (j < 4) ? a0[j] : a1[j - 4];
          split3(x, xh.s[j], xm.s[j], xl.s[j]);
        }
        *(uint4*)&sAh[t * 8] = xh.v;
        *(uint4*)&sAm[t * 8] = xm.v;
        *(uint4*)&sAl[t * 8] = xl.v;
      }
      __syncthreads();

      bf16x8 ah[2], am[2], al[2], bh[2], bm[2], bl[2];
#pragma unroll
      for (int rt = 0; rt < 2; ++rt) {
        int off = swz(waveM * 32 + rt * 16 + l15, q) * 8;
        ah[rt] = *(const bf16x8*)&sAh[off];
        am[rt] = *(const bf16x8*)&sAm[off];
        al[rt] = *(const bf16x8*)&sAl[off];
      }
#pragma unroll
      for (int ct = 0; ct < 2; ++ct) {
        int off = swz(waveN * 32 + ct * 16 + l15, q) * 8;
        bh[ct] = *(const bf16x8*)&sBh[off];
        bm[ct] = *(const bf16x8*)&sBm[off];
        bl[ct] = *(const bf16x8*)&sBl[off];
      }
#pragma unroll
      for (int rt = 0; rt < 2; ++rt)
#pragma unroll
        for (int ct = 0; ct < 2; ++ct) {
          acc[rt][ct] = __builtin_amdgcn_mfma_f32_16x16x32_bf16(al[rt], bh[ct], acc[rt][ct], 0, 0, 0);
          acc[rt][ct] = __builtin_amdgcn_mfma_f32_16x16x32_bf16(ah[rt], bl[ct], acc[rt][ct], 0, 0, 0);
          acc[rt][ct] = __builtin_amdgcn_mfma_f32_16x16x32_bf16(am[rt], bm[ct], acc[rt][ct], 0, 0, 0);
          acc[rt][ct] = __builtin_amdgcn_mfma_f32_16x16x32_bf16(am[rt], bh[ct], acc[rt][ct], 0, 0, 0);
          acc[rt][ct] = __builtin_amdgcn_mfma_f32_16x16x32_bf16(ah[rt], bm[ct], acc[rt][ct], 0, 0, 0);
          acc[rt][ct] = __builtin_amdgcn_mfma_f32_16x16x32_bf16(ah[rt], bh[ct], acc[rt][ct], 0, 0, 0);
        }
      __syncthreads();
    }

#pragma unroll
    for (int rt = 0; rt < 2; ++rt)
#pragma unroll
      for (int ct = 0; ct < 2; ++ct)
#pragma unroll
        for (int i = 0; i < 4; ++i)
          unsafeAtomicAdd(&lg[(size_t)(tokBase + waveM * 32 + rt * 16 + q * 4 + i) * NE +
                              waveN * 32 + ct * 16 + l15], acc[rt][ct][i]);
  } else {
    // ================= diff body =================
    unsigned short* sAh = smem;           // 256 units
    unsigned short* sAl = smem + 2048;
    unsigned short* sBh = smem + 4096;    // 1024 units
    unsigned short* sBl = smem + 12288;

    const int nBase = blockIdx.x * 256;

    f32x4 acc[4][4] = {};

    for (int kb = 0; kb < HD / 32; ++kb) {
      const int k0 = kb * 32;
      // A: fp32 load (issued first), rne hi/lo split, ds_write
      const float* g = hs + (size_t)(tokBase + srow) * HD + k0 + sq * 8;
      fv4 v0 = *(const fv4*)g, v1 = *(const fv4*)(g + 4);
      // B: 1024 units per plane, 4 per thread, async 16B DMA
#pragma unroll
      for (int j = 0; j < 4; ++j) {
        int s = t + j * 256;
        int brow = s >> 2, bq = (s & 3) ^ ((s >> 4) & 3);
        const size_t gb = (size_t)(nBase + brow) * HD + k0 + bq * 8;
        gload16(w1h + gb, &sBh[s * 8]);
        gload16(w1l + gb, &sBl[s * 8]);
      }
      {
        union { unsigned short s[8]; uint4 v; } ph, pl;
#pragma unroll
        for (int jj = 0; jj < 8; ++jj) {
          float x = (jj < 4) ? v0[jj] : v1[jj - 4];
          unsigned short h = bf_rne(x);
          ph.s[jj] = h;
          pl.s[jj] = bf_rne(x - bf_to_f(h));
        }
        *(uint4*)&sAh[t * 8] = ph.v;
        *(uint4*)&sAl[t * 8] = pl.v;
      }
      __syncthreads();

      bf16x8 bh[4], bl[4];
#pragma unroll
      for (int ct = 0; ct < 4; ++ct) {
        int off = swz(w * 64 + ct * 16 + l15, q) * 8;
        bh[ct] = *(const bf16x8*)&sBh[off];
        bl[ct] = *(const bf16x8*)&sBl[off];
      }
#pragma unroll
      for (int rt = 0; rt < 4; ++rt) {
        int off = swz(rt * 16 + l15, q) * 8;
        bf16x8 ah = *(const bf16x8*)&sAh[off];
        bf16x8 al = *(const bf16x8*)&sAl[off];
#pragma unroll
        for (int ct = 0; ct < 4; ++ct) {
          acc[rt][ct] = __builtin_amdgcn_mfma_f32_16x16x32_bf16(ah, bh[ct], acc[rt][ct], 0, 0, 0);
          acc[rt][ct] = __builtin_amdgcn_mfma_f32_16x16x32_bf16(ah, bl[ct], acc[rt][ct], 0, 0, 0);
          acc[rt][ct] = __builtin_amdgcn_mfma_f32_16x16x32_bf16(al, bh[ct], acc[rt][ct], 0, 0, 0);
        }
      }
      __syncthreads();
    }

    // epilogue: x1 + b1 -> silu -> *w2 -> reduce wave's 64 cols -> atomic x2
    // (unchanged: 8 contributors/token = 4 col-waves x 2 n-chunks, same tree)
    float b1v[4], w2v[4];
#pragma unroll
    for (int ct = 0; ct < 4; ++ct) {
      int c = nBase + w * 64 + ct * 16 + l15;
      b1v[ct] = b1[c];
      w2v[ct] = w2[c];
    }
#pragma unroll
    for (int rt = 0; rt < 4; ++rt) {
#pragma unroll
      for (int i = 0; i < 4; ++i) {
        float s = 0.f;
#pragma unroll
        for (int ct = 0; ct < 4; ++ct) {
          float x1 = acc[rt][ct][i] + b1v[ct];
          float h1 = x1 / (1.f + expf(-x1));   // silu
          s += h1 * w2v[ct];
        }
        s += __shfl_xor(s, 1, 64);
        s += __shfl_xor(s, 2, 64);
        s += __shfl_xor(s, 4, 64);
        s += __shfl_xor(s, 8, 64);
        if (l15 == 0)
          unsafeAtomicAdd(&x2[tokBase + rt * 16 + q * 4 + i], s);
      }
    }
  }
}

// ---------- K3: per-token routing (one wave = one token's 64 experts) -----
__global__ __launch_bounds__(256)
void k_route(const float* __restrict__ lg, const float* __restrict__ x2,
             const float* __restrict__ b2, float* __restrict__ out,
             double* __restrict__ tpe, double* __restrict__ ks_es) {
  const int t = threadIdx.x, wv = t >> 6, e = t & 63;
  const int base = blockIdx.x * 64 + wv * 16;
  const float b2v = b2[0];
  double tacc = 0.0, kacc = 0.0, eacc = 0.0;

  for (int it = 0; it < 16; ++it) {
    const int tok = base + it;
    const size_t idx = (size_t)tok * NE + e;
    float my = lg[idx];
    float xv = x2[tok] + b2v;
    float d = 1.f / (1.f + expf(-xv));
    float kf = 4.f + 8.f * d;
    int ki = (int)rintf(kf);             // round-half-even, matches jnp.round
    ki = min(max(ki, 4), 12);

    int r = 0;  // stable descending rank
#pragma unroll
    for (int s = 1; s < 64; ++s) {
      int src = (e + s) & 63;
      float o = __shfl(my, src, 64);
      r += (o > my || (o == my && src < e)) ? 1 : 0;
    }
    float m = my;
#pragma unroll
    for (int off = 1; off < 64; off <<= 1) m = fmaxf(m, __shfl_xor(m, off, 64));
    float ex = (r < ki) ? expf(my - m) : 0.f;
    float sm = ex;
#pragma unroll
    for (int off = 1; off < 64; off <<= 1) sm += __shfl_xor(sm, off, 64);
    float wgt = ex / sm;
    out[idx] = wgt;

    tacc += (double)wgt;
    kacc += (double)kf;
    eacc += (double)(d * logf(d + 1e-8f) + (1.f - d) * logf(1.f - d + 1e-8f));
  }
  unsafeAtomicAdd(&tpe[e], tacc);
  if (e == 0) {
    unsafeAtomicAdd(&ks_es[0], kacc);
    unsafeAtomicAdd(&ks_es[1], eacc);
  }
}

// ---------- K4: aux loss ----------
__global__ void k_aux(const double* __restrict__ tpe,
                      const double* __restrict__ ks_es,
                      float* __restrict__ out) {
  const int e = threadIdx.x;  // 64 threads
  double x = tpe[e];
  double s = x;
#pragma unroll
  for (int off = 1; off < 64; off <<= 1) s += __shfl_xor(s, off, 64);
  double mean = s / 64.0;
  double dv = x - mean, v = dv * dv;
#pragma unroll
  for (int off = 1; off < 64; off <<= 1) v += __shfl_xor(v, off, 64);
  double var = v / 63.0;                       // ddof=1
  double avgk = ks_es[0] / (double)NTOK;
  double kp = 8.0 - avgk;
  kp = kp > 0.0 ? kp * kp : 0.0;               // relu(BASE_K-avg_k)^2
  double bal = var / (mean + 1e-8);
  double aux = 0.01 * (kp + bal) + 0.001 * (ks_es[1] / (double)NTOK);
  if (e == 0) out[(size_t)NTOK * NE] = (float)aux;
}

// ---------- launch ----------
extern "C" void kernel_launch(void* const* d_in, const int* in_sizes, int n_in,
                              void* d_out, int out_size, void* d_ws, size_t ws_size,
                              hipStream_t stream) {
  const float* hs = (const float*)d_in[0];
  const float* gw = (const float*)d_in[1];
  const float* w1 = (const float*)d_in[2];
  const float* b1 = (const float*)d_in[3];
  const float* w2 = (const float*)d_in[4];
  const float* b2 = (const float*)d_in[5];
  float* out = (float*)d_out;
  char* ws = (char*)d_ws;

  // ws layout (unchanged 8,454,672 B budget):
  //   [0,       4194304)  gate logits lg (fp32, atomically accumulated)
  //   [4194304, 4260368)  x2 / tpe / ks_es  (zeroed together with lg)
  //   [4260368, 6357520)  w1 hi plane (bf16)
  //   [6357520, 8454672)  w1 lo plane (bf16)
  // gw h/m/l planes (786,432 B) staged in d_out; k_route overwrites d_out
  // afterwards (stream-ordered, every element rewritten).
  float* lg = (float*)ws;
  char* tail = ws + 4194304;
  float*  x2    = (float*)tail;              // 65,536 B
  double* tpe   = (double*)(tail + 65536);   // 512 B
  double* ks_es = (double*)(tail + 66048);   // 16 B
  unsigned short* w1h = (unsigned short*)(ws + 4260368);
  unsigned short* w1l = (unsigned short*)(ws + 6357520);
  unsigned short* gwh = (unsigned short*)d_out;
  unsigned short* gwm = gwh + NE * HD;
  unsigned short* gwl = gwm + NE * HD;

  // 1040 zero blocks + 512 w1-split blocks + 64 gw-split blocks
  k_pre<<<1616, 256, 0, stream>>>((uint4*)ws, w1, w1h, w1l, gw, gwh, gwm, gwl);
  k_main<<<dim3(2, NTOK / 64, 2), 256, 0, stream>>>(hs, gwh, gwm, gwl, lg,
                                                    w1h, w1l, b1, w2, x2);
  k_route<<<NTOK / 64, 256, 0, stream>>>(lg, x2, b2, out, tpe, ks_es);
  k_aux<<<1, 64, 0, stream>>>(tpe, ks_es, out);
}